// Round 6
// baseline (5671.929 us; speedup 1.0000x reference)
//
#include <hip/hip_runtime.h>
#include <math.h>

#define SEQ 2048
#define BATCH 64
#define INF 256
#define HID 256
#define NL 2

// ---------------------------------------------------------------------------
// Phase A: pre[l][m][h] = sum_i x[m][i] * W[l][h][i] + bias[l][h]
// (unchanged — ~550 us; attack after rnn_kernel hits its floor)
// ---------------------------------------------------------------------------
__global__ __launch_bounds__(256) void xw_kernel(
    const float* __restrict__ x,
    const float* __restrict__ W,
    const float* __restrict__ bias,
    float* __restrict__ pre0,
    float* __restrict__ pre1)
{
    __shared__ float As[64][68];
    __shared__ float Bs[64][68];

    const int mb = blockIdx.x * 64;
    const int nb = blockIdx.y * 64;
    const int l  = nb >> 8;
    const int hb = nb & 255;

    const int tid = threadIdx.x;
    const int tx = tid & 15;
    const int ty = tid >> 4;

    const float* Wl = W + (size_t)l * HID * INF;

    float acc[4][4] = {};

    const int lrow = tid >> 4;
    const int lkq  = tid & 15;

    for (int kb = 0; kb < INF; kb += 64) {
        #pragma unroll
        for (int rr = 0; rr < 4; ++rr) {
            const int m = lrow + rr * 16;
            float4 va = *(const float4*)&x[(size_t)(mb + m) * INF + kb + lkq * 4];
            As[lkq*4 + 0][m] = va.x; As[lkq*4 + 1][m] = va.y;
            As[lkq*4 + 2][m] = va.z; As[lkq*4 + 3][m] = va.w;
            float4 vb = *(const float4*)&Wl[(size_t)(hb + m) * INF + kb + lkq * 4];
            Bs[lkq*4 + 0][m] = vb.x; Bs[lkq*4 + 1][m] = vb.y;
            Bs[lkq*4 + 2][m] = vb.z; Bs[lkq*4 + 3][m] = vb.w;
        }
        __syncthreads();

        #pragma unroll 8
        for (int k = 0; k < 64; ++k) {
            float4 a = *(const float4*)&As[k][ty * 4];
            float4 b = *(const float4*)&Bs[k][tx * 4];
            acc[0][0] = fmaf(a.x, b.x, acc[0][0]);
            acc[0][1] = fmaf(a.x, b.y, acc[0][1]);
            acc[0][2] = fmaf(a.x, b.z, acc[0][2]);
            acc[0][3] = fmaf(a.x, b.w, acc[0][3]);
            acc[1][0] = fmaf(a.y, b.x, acc[1][0]);
            acc[1][1] = fmaf(a.y, b.y, acc[1][1]);
            acc[1][2] = fmaf(a.y, b.z, acc[1][2]);
            acc[1][3] = fmaf(a.y, b.w, acc[1][3]);
            acc[2][0] = fmaf(a.z, b.x, acc[2][0]);
            acc[2][1] = fmaf(a.z, b.y, acc[2][1]);
            acc[2][2] = fmaf(a.z, b.z, acc[2][2]);
            acc[2][3] = fmaf(a.z, b.w, acc[2][3]);
            acc[3][0] = fmaf(a.w, b.x, acc[3][0]);
            acc[3][1] = fmaf(a.w, b.y, acc[3][1]);
            acc[3][2] = fmaf(a.w, b.z, acc[3][2]);
            acc[3][3] = fmaf(a.w, b.w, acc[3][3]);
        }
        __syncthreads();
    }

    float bv[4];
    #pragma unroll
    for (int j = 0; j < 4; ++j)
        bv[j] = bias[l * HID + hb + tx * 4 + j];

    float* dst = (l == 0) ? pre0 : pre1;
    #pragma unroll
    for (int i = 0; i < 4; ++i) {
        float4 o;
        o.x = acc[i][0] + bv[0];
        o.y = acc[i][1] + bv[1];
        o.z = acc[i][2] + bv[2];
        o.w = acc[i][3] + bv[3];
        *(float4*)&dst[(size_t)(mb + ty * 4 + i) * HID + hb + tx * 4] = o;
    }
}

// fast tanh: clamp + hw exp. |err| ~1e-6 rel, fine vs 2e-2 threshold.
__device__ __forceinline__ float tanh_fast(float x) {
    float xc = fminf(fmaxf(x, -12.0f), 12.0f);
    float e  = __expf(2.0f * xc);            // v_exp_f32 path
    return __fdividef(e - 1.0f, e + 1.0f);   // v_rcp + mul
}

// ---------------------------------------------------------------------------
// Phase B v4: 128 blocks x 256 threads, launch_bounds(256,1) -> 512-VGPR cap.
// Thread g owns output row g of U entirely: u4[64] = 256 VGPRs pinned, the
// full 256-term dot product is computed per-thread. NO reduction phase at
// all (no shfl, no partials LDS). h lives in LDS (2.5 KB ping-pong); every
// thread reads the same chunk -> pure LDS broadcast, conflict-free.
// One barrier per step. Per-step floor: 256 FMA x 2cyc = 512 cyc.
// Round-3/4 lesson: 1024-thread block capped regs at ~64/wave -> U could
// never be register-resident; this shape makes the budget trivially enough.
// ---------------------------------------------------------------------------
__global__ __launch_bounds__(256, 1) void rnn_kernel(
    const float* __restrict__ h0,
    const float* __restrict__ U,
    const float* pre0,
    const float* pre1,
    float* out,
    float* hn)
{
    __shared__ float4 hbuf[2][64];   // h as 64 float4 chunks, double-buffered

    const int l = blockIdx.x >> 6;
    const int b = blockIdx.x & 63;
    const int g = threadIdx.x;       // 0..255 — output row this thread owns

    // Pin the whole U row in registers (one-time, L2-amortized across the
    // 64 blocks sharing each layer's U).
    float4 u4[64];
    const float* Urow = U + (size_t)l * HID * HID + (size_t)g * HID;
    #pragma unroll
    for (int q = 0; q < 64; ++q)
        u4[q] = *(const float4*)&Urow[q * 4];
    #pragma unroll
    for (int q = 0; q < 64; ++q)
        asm volatile("" : "+v"(u4[q].x), "+v"(u4[q].y), "+v"(u4[q].z), "+v"(u4[q].w));

    ((float*)&hbuf[0][0])[g] = h0[(size_t)l * BATCH * HID + (size_t)b * HID + g];
    __syncthreads();

    const float* pre = (l == 0) ? pre0 : pre1;
    const size_t bh = (size_t)b * HID + g;

    float preCur = pre[bh];          // t = 0
    float v = 0.0f;
    int cur = 0;

    for (int t = 0; t < SEQ; ++t) {
        // prefetch next pre early: HBM/L2 latency hides under 512 cyc of FMA
        float preNext = (t + 1 < SEQ) ? pre[(size_t)(t + 1) * BATCH * HID + bh] : 0.0f;

        float a0 = 0.f, a1 = 0.f, a2 = 0.f, a3 = 0.f;
        const float4* hb = hbuf[cur];
        #pragma unroll
        for (int q = 0; q < 64; ++q) {
            float4 hv = hb[q];       // broadcast ds_read_b128
            a0 = fmaf(u4[q].x, hv.x, a0);
            a1 = fmaf(u4[q].y, hv.y, a1);
            a2 = fmaf(u4[q].z, hv.z, a2);
            a3 = fmaf(u4[q].w, hv.w, a3);
        }
        v = tanh_fast(((a0 + a1) + (a2 + a3)) + preCur);

        ((float*)&hbuf[cur ^ 1][0])[g] = v;
        if (l == 1)
            out[(size_t)t * BATCH * HID + bh] = v;

        preCur = preNext;
        cur ^= 1;
        __syncthreads();             // single barrier: dbl-buffer makes it safe
    }

    hn[(size_t)l * BATCH * HID + bh] = v;
}

extern "C" void kernel_launch(void* const* d_in, const int* in_sizes, int n_in,
                              void* d_out, int out_size, void* d_ws, size_t ws_size,
                              hipStream_t stream) {
    const float* x  = (const float*)d_in[0];   // [SEQ][B][IN]
    const float* h0 = (const float*)d_in[1];   // [L][B][H]
    const float* W  = (const float*)d_in[2];   // [L][H][IN]
    const float* U  = (const float*)d_in[3];   // [L][H][H]
    const float* bs = (const float*)d_in[4];   // [L][H]

    float* out  = (float*)d_out;               // [SEQ][B][H] then [L][B][H]
    float* pre0 = (float*)d_ws;                // l=0 preacts (134 MB)
    float* pre1 = out;                         // l=1 preacts staged in-place
    float* hn   = out + (size_t)SEQ * BATCH * HID;

    dim3 gridA(SEQ * BATCH / 64, (NL * HID) / 64);
    xw_kernel<<<gridA, 256, 0, stream>>>(x, W, bs, pre0, pre1);

    rnn_kernel<<<NL * BATCH, 256, 0, stream>>>(h0, U, pre0, pre1, out, hn);
}

// Round 7
// 2136.798 us; speedup vs baseline: 2.6544x; 2.6544x over previous
//
#include <hip/hip_runtime.h>
#include <math.h>

#define SEQ 2048
#define BATCH 64
#define INF 256
#define HID 256
#define NL 2

typedef __attribute__((ext_vector_type(2))) _Float16 half2_t;

// ---------------------------------------------------------------------------
// Phase A: pre[l][m][h] = sum_i x[m][i] * W[l][h][i] + bias[l][h]
// (unchanged — ~550 us; attack with MFMA once rnn hits its floor)
// ---------------------------------------------------------------------------
__global__ __launch_bounds__(256) void xw_kernel(
    const float* __restrict__ x,
    const float* __restrict__ W,
    const float* __restrict__ bias,
    float* __restrict__ pre0,
    float* __restrict__ pre1)
{
    __shared__ float As[64][68];
    __shared__ float Bs[64][68];

    const int mb = blockIdx.x * 64;
    const int nb = blockIdx.y * 64;
    const int l  = nb >> 8;
    const int hb = nb & 255;

    const int tid = threadIdx.x;
    const int tx = tid & 15;
    const int ty = tid >> 4;

    const float* Wl = W + (size_t)l * HID * INF;

    float acc[4][4] = {};

    const int lrow = tid >> 4;
    const int lkq  = tid & 15;

    for (int kb = 0; kb < INF; kb += 64) {
        #pragma unroll
        for (int rr = 0; rr < 4; ++rr) {
            const int m = lrow + rr * 16;
            float4 va = *(const float4*)&x[(size_t)(mb + m) * INF + kb + lkq * 4];
            As[lkq*4 + 0][m] = va.x; As[lkq*4 + 1][m] = va.y;
            As[lkq*4 + 2][m] = va.z; As[lkq*4 + 3][m] = va.w;
            float4 vb = *(const float4*)&Wl[(size_t)(hb + m) * INF + kb + lkq * 4];
            Bs[lkq*4 + 0][m] = vb.x; Bs[lkq*4 + 1][m] = vb.y;
            Bs[lkq*4 + 2][m] = vb.z; Bs[lkq*4 + 3][m] = vb.w;
        }
        __syncthreads();

        #pragma unroll 8
        for (int k = 0; k < 64; ++k) {
            float4 a = *(const float4*)&As[k][ty * 4];
            float4 b = *(const float4*)&Bs[k][tx * 4];
            acc[0][0] = fmaf(a.x, b.x, acc[0][0]);
            acc[0][1] = fmaf(a.x, b.y, acc[0][1]);
            acc[0][2] = fmaf(a.x, b.z, acc[0][2]);
            acc[0][3] = fmaf(a.x, b.w, acc[0][3]);
            acc[1][0] = fmaf(a.y, b.x, acc[1][0]);
            acc[1][1] = fmaf(a.y, b.y, acc[1][1]);
            acc[1][2] = fmaf(a.y, b.z, acc[1][2]);
            acc[1][3] = fmaf(a.y, b.w, acc[1][3]);
            acc[2][0] = fmaf(a.z, b.x, acc[2][0]);
            acc[2][1] = fmaf(a.z, b.y, acc[2][1]);
            acc[2][2] = fmaf(a.z, b.z, acc[2][2]);
            acc[2][3] = fmaf(a.z, b.w, acc[2][3]);
            acc[3][0] = fmaf(a.w, b.x, acc[3][0]);
            acc[3][1] = fmaf(a.w, b.y, acc[3][1]);
            acc[3][2] = fmaf(a.w, b.z, acc[3][2]);
            acc[3][3] = fmaf(a.w, b.w, acc[3][3]);
        }
        __syncthreads();
    }

    float bv[4];
    #pragma unroll
    for (int j = 0; j < 4; ++j)
        bv[j] = bias[l * HID + hb + tx * 4 + j];

    float* dst = (l == 0) ? pre0 : pre1;
    #pragma unroll
    for (int i = 0; i < 4; ++i) {
        float4 o;
        o.x = acc[i][0] + bv[0];
        o.y = acc[i][1] + bv[1];
        o.z = acc[i][2] + bv[2];
        o.w = acc[i][3] + bv[3];
        *(float4*)&dst[(size_t)(mb + ty * 4 + i) * HID + hb + tx * 4] = o;
    }
}

// fast tanh: clamp + hw exp. |err| ~1e-6 rel.
__device__ __forceinline__ float tanh_fast(float x) {
    float xc = fminf(fmaxf(x, -12.0f), 12.0f);
    float e  = __expf(2.0f * xc);
    return __fdividef(e - 1.0f, e + 1.0f);
}

// packed f16 dot2 with fp32 accumulate (v_dot2_f32_f16); fallback = 2 fma
__device__ __forceinline__ float dot2(unsigned ua, unsigned ub, float c) {
#if __has_builtin(__builtin_amdgcn_fdot2)
    return __builtin_amdgcn_fdot2(__builtin_bit_cast(half2_t, ua),
                                  __builtin_bit_cast(half2_t, ub), c, false);
#else
    half2_t a = __builtin_bit_cast(half2_t, ua);
    half2_t b = __builtin_bit_cast(half2_t, ub);
    c = fmaf((float)a.x, (float)b.x, c);
    return fmaf((float)a.y, (float)b.y, c);
#endif
}

__device__ __forceinline__ unsigned pk16(float a, float b) {
#if __has_builtin(__builtin_amdgcn_cvt_pkrtz)
    return __builtin_bit_cast(unsigned, __builtin_amdgcn_cvt_pkrtz(a, b));
#else
    half2_t h; h.x = (_Float16)a; h.y = (_Float16)b;
    return __builtin_bit_cast(unsigned, h);
#endif
}

// ---------------------------------------------------------------------------
// Phase B v5: f16/dot2 recurrence. 128 blocks x 512 threads,
// launch_bounds(512,2) -> 256-VGPR cap (8 waves = 1 block/CU).
//   g = tid>>1 (output row 0..255), c = tid&1 (k-half of 128 terms).
// U[l][g][c*128..+128) lives as 64 PACKED f16 pairs = 16 uint4 = 64 VGPRs
// (pinned; demand ~150 vs cap 256 — the slack rounds 3/4/6 never had).
// h: packed f16 pairs in LDS (2x512B ping-pong). Reads are 2-address
// broadcasts (conflict-free). Per step/thread: 16 ds_read_b128 + 64 dot2
// (fp32 accum) -> 1 shfl reduce -> tanh -> shfl-pair + cvt_pkrtz pack ->
// 1 uint32 LDS write -> single barrier. fp32 master values feed out/hn.
// ---------------------------------------------------------------------------
__global__ __launch_bounds__(512, 2) void rnn_kernel(
    const float* __restrict__ h0,
    const float* __restrict__ U,
    const float* pre0,
    const float* pre1,
    float* out,
    float* hn)
{
    __shared__ alignas(16) unsigned h16[2][128];   // packed f16 pairs

    const int l = blockIdx.x >> 6;
    const int b = blockIdx.x & 63;
    const int tid = threadIdx.x;
    const int g = tid >> 1;          // 0..255
    const int c = tid & 1;           // 0..1

    // Load + pack U row-half into 16 uint4 (64 packed pairs = 128 f16 terms)
    uint4 uu[16];
    const float* Urow = U + (size_t)l * HID * HID + (size_t)g * HID + c * 128;
    #pragma unroll
    for (int r = 0; r < 16; ++r) {
        float4 f0 = *(const float4*)&Urow[r * 8];
        float4 f1 = *(const float4*)&Urow[r * 8 + 4];
        uu[r].x = pk16(f0.x, f0.y);
        uu[r].y = pk16(f0.z, f0.w);
        uu[r].z = pk16(f1.x, f1.y);
        uu[r].w = pk16(f1.z, f1.w);
    }
    #pragma unroll
    for (int r = 0; r < 16; ++r)
        asm volatile("" : "+v"(uu[r].x), "+v"(uu[r].y), "+v"(uu[r].z), "+v"(uu[r].w));

    // h0 -> packed LDS buffer 0
    if (tid < 128) {
        const float* h0p = h0 + (size_t)l * BATCH * HID + (size_t)b * HID;
        h16[0][tid] = pk16(h0p[tid * 2], h0p[tid * 2 + 1]);
    }
    __syncthreads();

    const float* pre = (l == 0) ? pre0 : pre1;
    const size_t bh = (size_t)b * HID + g;

    float preCur = pre[bh];          // t = 0
    float v = 0.0f;
    int cur = 0;

    for (int t = 0; t < SEQ; ++t) {
        float preNext = (t + 1 < SEQ) ? pre[(size_t)(t + 1) * BATCH * HID + bh] : 0.0f;

        float a0 = 0.f, a1 = 0.f, a2 = 0.f, a3 = 0.f;
        const uint4* hc = (const uint4*)&h16[cur][c * 64];
        #pragma unroll
        for (int r = 0; r < 16; ++r) {
            uint4 w = hc[r];         // broadcast ds_read_b128 (2 addrs/wave)
            a0 = dot2(w.x, uu[r].x, a0);
            a1 = dot2(w.y, uu[r].y, a1);
            a2 = dot2(w.z, uu[r].z, a2);
            a3 = dot2(w.w, uu[r].w, a3);
        }
        float s = (a0 + a1) + (a2 + a3);
        s += __shfl_xor(s, 1);       // combine the two k-halves

        v = tanh_fast(s + preCur);

        float vp = __shfl_xor(v, 2); // partner row g^1's value
        if (c == 0) {
            if ((g & 1) == 0)
                h16[cur ^ 1][g >> 1] = pk16(v, vp);
            if (l == 1)
                out[(size_t)t * BATCH * HID + bh] = v;
        }
        preCur = preNext;
        cur ^= 1;
        __syncthreads();
    }

    if (c == 0)
        hn[(size_t)l * BATCH * HID + bh] = v;
}

extern "C" void kernel_launch(void* const* d_in, const int* in_sizes, int n_in,
                              void* d_out, int out_size, void* d_ws, size_t ws_size,
                              hipStream_t stream) {
    const float* x  = (const float*)d_in[0];   // [SEQ][B][IN]
    const float* h0 = (const float*)d_in[1];   // [L][B][H]
    const float* W  = (const float*)d_in[2];   // [L][H][IN]
    const float* U  = (const float*)d_in[3];   // [L][H][H]
    const float* bs = (const float*)d_in[4];   // [L][H]

    float* out  = (float*)d_out;               // [SEQ][B][H] then [L][B][H]
    float* pre0 = (float*)d_ws;                // l=0 preacts (134 MB)
    float* pre1 = out;                         // l=1 preacts staged in-place
    float* hn   = out + (size_t)SEQ * BATCH * HID;

    dim3 gridA(SEQ * BATCH / 64, (NL * HID) / 64);
    xw_kernel<<<gridA, 256, 0, stream>>>(x, W, bs, pre0, pre1);

    rnn_kernel<<<NL * BATCH, 512, 0, stream>>>(h0, U, pre0, pre1, out, hn);
}